// Round 1
// 606.158 us; speedup vs baseline: 1.0440x; 1.0440x over previous
//
#include <hip/hip_runtime.h>
#include <hip/hip_bf16.h>

// Problem constants (fixed by reference)
#define NN 8192
#define NMASK 8191
#define IND 3000
#define INDP 3008   // padded K for W1t rows: 3008*2B = 6016 bytes, 16B-aligned rows
#define H1 256
#define OUTD 64

typedef __bf16 bf16x8 __attribute__((ext_vector_type(8)));
typedef float floatx4 __attribute__((ext_vector_type(4)));

__device__ __forceinline__ unsigned short f2b(float f) {
    __hip_bfloat16 h = __float2bfloat16(f);
    unsigned short u;
    __builtin_memcpy(&u, &h, 2);
    return u;
}

// ---------------- ws-size probe ----------------

__global__ void k_probe(float code, float* out) {
    if (threadIdx.x == 0 && blockIdx.x == 0) out[0] = code;
}

// ---------------- index width detection (both arrays, one launch) ----------------

__global__ void k_detect2(const unsigned* __restrict__ a, const unsigned* __restrict__ b,
                          int pairs, int* __restrict__ flags) {
    const unsigned* r = (blockIdx.x == 0) ? a : b;
    __shared__ int cnt;
    if (threadIdx.x == 0) cnt = 0;
    __syncthreads();
    int z = 0;
    for (int k = threadIdx.x; k < pairs; k += blockDim.x)
        if (r[2 * k + 1] == 0u) z++;
    atomicAdd(&cnt, z);
    __syncthreads();
    if (threadIdx.x == 0) flags[blockIdx.x] = (cnt > pairs / 2) ? 1 : 0;
}

// ---------------- normalize eidx + perm AND degree accumulation, one pass ----------------

__global__ void k_prep(const unsigned* __restrict__ eraw, const unsigned* __restrict__ praw,
                       const int* __restrict__ flags, int* __restrict__ eidx32,
                       int* __restrict__ perm32, int* __restrict__ deg, int E, int n) {
    int i = blockIdx.x * blockDim.x + threadIdx.x;
    if (i < 2 * E) {
        unsigned v = flags[0] ? eraw[2 * (size_t)i] : eraw[i];
        int x = (int)(v & (unsigned)NMASK);
        eidx32[i] = x;
        if (i >= E) atomicAdd(&deg[x], 1);  // dst half drives in-degree
    } else {
        int j = i - 2 * E;
        if (j < n) {
            unsigned v = flags[1] ? praw[2 * (size_t)j] : praw[j];
            perm32[j] = (int)(v & (unsigned)NMASK);
        }
    }
}

// ---------------- CSR scan ----------------

__global__ __launch_bounds__(1024) void k_scan(const int* __restrict__ deg,
                                               int* __restrict__ row_ptr,
                                               int* __restrict__ cursor,
                                               float* __restrict__ dinv, int n) {
    __shared__ int sums[1024];
    int t = threadIdx.x;
    int per = n / 1024;  // 8
    int base = t * per;
    int s = 0;
    for (int u = 0; u < per; ++u) s += deg[base + u];
    sums[t] = s;
    __syncthreads();
    for (int off = 1; off < 1024; off <<= 1) {
        int v = (t >= off) ? sums[t - off] : 0;
        __syncthreads();
        sums[t] += v;
        __syncthreads();
    }
    int run = (t == 0) ? 0 : sums[t - 1];
    for (int u = 0; u < per; ++u) {
        int i = base + u;
        row_ptr[i] = run;
        cursor[i] = run;
        int d = deg[i];
        dinv[i] = rsqrtf((float)(1 + d));
        run += d;
    }
    if (t == 1023) row_ptr[n] = run;
}

__global__ void k_scatter(const int* __restrict__ src, const int* __restrict__ dst,
                          int* __restrict__ cursor, int* __restrict__ col, int E) {
    int e = blockIdx.x * blockDim.x + threadIdx.x;
    if (e < E) {
        int d = dst[e];
        int p = atomicAdd(&cursor[d], 1);
        if (p >= 0 && p < E) col[p] = src[e];
    }
}

// fp32 weight -> bf16 transposed with padded leading dim (out[c][r], ld stride)
__global__ void k_transpose_f2b(const float* __restrict__ in,
                                __hip_bfloat16* __restrict__ out, int R, int C, int ld) {
    int idx = blockIdx.x * blockDim.x + threadIdx.x;
    if (idx < R * C) {
        int r = idx / C, c = idx % C;
        out[(size_t)c * ld + r] = __float2bfloat16(in[idx]);
    }
}

// ---------------- GEMM1: xw1[8192][256] = gene(fp32) @ W1 ----------------
// BM=64 BN=64 BK=64 (47 K-iters, half the barriers of BK=32).
// grid = (N/64, M/64): 4 consecutive blocks share one A panel -> L2/LLC reuse.

__global__ __launch_bounds__(256) void k_gemm1(const float* __restrict__ A,
                                               const __hip_bfloat16* __restrict__ Bt,
                                               float* __restrict__ C) {
    __shared__ __align__(16) unsigned short As[64 * 72];  // stride 72: <=2-way bank alias
    __shared__ __align__(16) unsigned short Bs[64 * 72];
    int t = threadIdx.x;
    int n0 = blockIdx.x * 64;  // col panel (4), fastest varying
    int m0 = blockIdx.y * 64;  // row panel (128)
    int lane = t & 63;
    int w = t >> 6;
    int srow = t >> 2;           // staging row 0..63
    int schunk = (t & 3) * 16;   // k element offset 0,16,32,48
    const float* Arow = A + (size_t)(m0 + srow) * IND + schunk;
    const unsigned short* Brow = (const unsigned short*)Bt + (size_t)(n0 + srow) * INDP + schunk;

    floatx4 acc0 = {0.f, 0.f, 0.f, 0.f}, acc1 = acc0, acc2 = acc0, acc3 = acc0;
    int msub = w * 16;
    int arow = msub + (lane & 15);
    int koff = (lane >> 4) * 8;
    int nlo = lane & 15;

    for (int k0 = 0; k0 < IND; k0 += 64) {
        uint4 av0 = make_uint4(0u, 0u, 0u, 0u), av1 = av0, bv0 = av0, bv1 = av0;
        // sub-chunk s covers k in [k0+schunk+8s, +8); K%8==0 so in-bounds start => full chunk
        {
            int kk = k0 + schunk;
            if (kk < IND) {
                const float* ap = Arow + k0;
                float4 f0 = *reinterpret_cast<const float4*>(ap);
                float4 f1 = *reinterpret_cast<const float4*>(ap + 4);
                unsigned short t8[8] = {f2b(f0.x), f2b(f0.y), f2b(f0.z), f2b(f0.w),
                                        f2b(f1.x), f2b(f1.y), f2b(f1.z), f2b(f1.w)};
                __builtin_memcpy(&av0, t8, 16);
                bv0 = *reinterpret_cast<const uint4*>(Brow + k0);
            }
            if (kk + 8 < IND) {
                const float* ap = Arow + k0 + 8;
                float4 f0 = *reinterpret_cast<const float4*>(ap);
                float4 f1 = *reinterpret_cast<const float4*>(ap + 4);
                unsigned short t8[8] = {f2b(f0.x), f2b(f0.y), f2b(f0.z), f2b(f0.w),
                                        f2b(f1.x), f2b(f1.y), f2b(f1.z), f2b(f1.w)};
                __builtin_memcpy(&av1, t8, 16);
                bv1 = *reinterpret_cast<const uint4*>(Brow + k0 + 8);
            }
        }
        __syncthreads();
        *reinterpret_cast<uint4*>(&As[srow * 72 + schunk]) = av0;
        *reinterpret_cast<uint4*>(&As[srow * 72 + schunk + 8]) = av1;
        *reinterpret_cast<uint4*>(&Bs[srow * 72 + schunk]) = bv0;
        *reinterpret_cast<uint4*>(&Bs[srow * 72 + schunk + 8]) = bv1;
        __syncthreads();
#pragma unroll
        for (int ks = 0; ks < 64; ks += 32) {
            bf16x8 af = *reinterpret_cast<const bf16x8*>(&As[arow * 72 + ks + koff]);
            bf16x8 b0 = *reinterpret_cast<const bf16x8*>(&Bs[(0 + nlo) * 72 + ks + koff]);
            bf16x8 b1 = *reinterpret_cast<const bf16x8*>(&Bs[(16 + nlo) * 72 + ks + koff]);
            bf16x8 b2 = *reinterpret_cast<const bf16x8*>(&Bs[(32 + nlo) * 72 + ks + koff]);
            bf16x8 b3 = *reinterpret_cast<const bf16x8*>(&Bs[(48 + nlo) * 72 + ks + koff]);
            acc0 = __builtin_amdgcn_mfma_f32_16x16x32_bf16(af, b0, acc0, 0, 0, 0);
            acc1 = __builtin_amdgcn_mfma_f32_16x16x32_bf16(af, b1, acc1, 0, 0, 0);
            acc2 = __builtin_amdgcn_mfma_f32_16x16x32_bf16(af, b2, acc2, 0, 0, 0);
            acc3 = __builtin_amdgcn_mfma_f32_16x16x32_bf16(af, b3, acc3, 0, 0, 0);
        }
    }
    // C/D layout: col = lane&15, row = (lane>>4)*4 + r   [verified m89/m91]
    int crow = msub + (lane >> 4) * 4;
    int ccol = lane & 15;
    floatx4 accs[4] = {acc0, acc1, acc2, acc3};
#pragma unroll
    for (int j = 0; j < 4; ++j) {
#pragma unroll
        for (int r = 0; r < 4; ++r) {
            C[(size_t)(m0 + crow + r) * H1 + (n0 + j * 16 + ccol)] = accs[j][r];
        }
    }
}

// ---------------- GEMM2: hw_all = h_all(bf16) @ W2, BM=64 BN=64 BK=32 ----------------

__global__ __launch_bounds__(256) void k_gemm2(const __hip_bfloat16* __restrict__ A,
                                               const __hip_bfloat16* __restrict__ Bt,
                                               float* __restrict__ C,
                                               int M, int N, int K) {
    __shared__ __align__(16) unsigned short As[64 * 40];
    __shared__ __align__(16) unsigned short Bs[64 * 40];
    int t = threadIdx.x;
    int m0 = blockIdx.x * 64;
    int n0 = blockIdx.y * 64;
    int lane = t & 63;
    int w = t >> 6;
    int srow = t >> 2;
    int schunk = (t & 3) * 8;
    size_t aoff = (size_t)(m0 + srow) * K + schunk;
    const unsigned short* Brow = (const unsigned short*)Bt + (size_t)(n0 + srow) * K + schunk;

    floatx4 acc0 = {0.f, 0.f, 0.f, 0.f}, acc1 = acc0, acc2 = acc0, acc3 = acc0;
    int msub = w * 16;
    int arow = msub + (lane & 15);
    int koff = (lane >> 4) * 8;
    int nlo = lane & 15;

    for (int k0 = 0; k0 < K; k0 += 32) {
        uint4 av = *reinterpret_cast<const uint4*>((const unsigned short*)A + aoff + k0);
        uint4 bv = *reinterpret_cast<const uint4*>(Brow + k0);
        __syncthreads();
        *reinterpret_cast<uint4*>(&As[srow * 40 + schunk]) = av;
        *reinterpret_cast<uint4*>(&Bs[srow * 40 + schunk]) = bv;
        __syncthreads();
        bf16x8 af = *reinterpret_cast<const bf16x8*>(&As[arow * 40 + koff]);
        bf16x8 bf0 = *reinterpret_cast<const bf16x8*>(&Bs[(0 + nlo) * 40 + koff]);
        bf16x8 bf1 = *reinterpret_cast<const bf16x8*>(&Bs[(16 + nlo) * 40 + koff]);
        bf16x8 bf2 = *reinterpret_cast<const bf16x8*>(&Bs[(32 + nlo) * 40 + koff]);
        bf16x8 bf3 = *reinterpret_cast<const bf16x8*>(&Bs[(48 + nlo) * 40 + koff]);
        acc0 = __builtin_amdgcn_mfma_f32_16x16x32_bf16(af, bf0, acc0, 0, 0, 0);
        acc1 = __builtin_amdgcn_mfma_f32_16x16x32_bf16(af, bf1, acc1, 0, 0, 0);
        acc2 = __builtin_amdgcn_mfma_f32_16x16x32_bf16(af, bf2, acc2, 0, 0, 0);
        acc3 = __builtin_amdgcn_mfma_f32_16x16x32_bf16(af, bf3, acc3, 0, 0, 0);
    }
    int crow = msub + (lane >> 4) * 4;
    int ccol = lane & 15;
    floatx4 accs[4] = {acc0, acc1, acc2, acc3};
#pragma unroll
    for (int j = 0; j < 4; ++j) {
#pragma unroll
        for (int r = 0; r < 4; ++r) {
            C[(size_t)(m0 + crow + r) * N + (n0 + j * 16 + ccol)] = accs[j][r];
        }
    }
}

// ---------------- GCN aggregation layer 1 (256 cols, both graphs) ----------------

__global__ __launch_bounds__(256) void k_agg1(const float* __restrict__ xw1,
                                              const int* __restrict__ row_ptr,
                                              const int* __restrict__ col,
                                              const float* __restrict__ dinv,
                                              const int* __restrict__ perm,
                                              const float* __restrict__ b1,
                                              __hip_bfloat16* __restrict__ h_all, int n) {
    __shared__ int colS[64];
    __shared__ int pcolS[64];
    __shared__ float wS[64];
    int i = blockIdx.x;
    int c = threadIdx.x;
    float di = dinv[i];
    int pi = perm[i];
    float sw = di * di;
    float acc = sw * xw1[(size_t)i * H1 + c];
    float accc = sw * xw1[(size_t)pi * H1 + c];
    int s = row_ptr[i], e = row_ptr[i + 1];
    for (int base = s; base < e; base += 64) {
        int cnt = min(64, e - base);
        __syncthreads();
        if (c < cnt) {
            int j = col[base + c];
            colS[c] = j;
            wS[c] = di * dinv[j];
            pcolS[c] = perm[j];
        }
        __syncthreads();
#pragma unroll 4
        for (int u = 0; u < cnt; ++u) {
            float wv = wS[u];
            acc += wv * xw1[(size_t)colS[u] * H1 + c];
            accc += wv * xw1[(size_t)pcolS[u] * H1 + c];
        }
    }
    float b = b1[c];
    h_all[(size_t)i * H1 + c] = __float2bfloat16(fmaxf(acc + b, 0.f));
    h_all[(size_t)(n + i) * H1 + c] = __float2bfloat16(fmaxf(accc + b, 0.f));
}

// ---------------- GCN aggregation layer 2 (64 cols, both graphs, fp32) ----------------

__global__ __launch_bounds__(256) void k_agg2(const float* __restrict__ hw_all,
                                              const int* __restrict__ row_ptr,
                                              const int* __restrict__ col,
                                              const float* __restrict__ dinv,
                                              const float* __restrict__ b2,
                                              float* __restrict__ x1_all,
                                              float* __restrict__ out_x1, int n) {
    int lane = threadIdx.x & 63;
    int i = blockIdx.x * 4 + (threadIdx.x >> 6);
    float di = dinv[i];
    float sw = di * di;
    float acc = sw * hw_all[(size_t)i * OUTD + lane];
    float accc = sw * hw_all[(size_t)(n + i) * OUTD + lane];
    int s = row_ptr[i], e = row_ptr[i + 1];
#pragma unroll 4
    for (int t = s; t < e; ++t) {
        int j = col[t];
        float wv = di * dinv[j];
        acc += wv * hw_all[(size_t)j * OUTD + lane];
        accc += wv * hw_all[(size_t)(n + j) * OUTD + lane];
    }
    float b = b2[lane];
    float v = fmaxf(acc + b, 0.f);
    float vc = fmaxf(accc + b, 0.f);
    x1_all[(size_t)i * OUTD + lane] = v;
    x1_all[(size_t)(n + i) * OUTD + lane] = vc;
    out_x1[(size_t)i * OUTD + lane] = v;
}

// ---------------- readout + bilinear, fused ----------------
// vsum = mask @ x1 (both graphs), /rowsum, L2-norm, sigmoid -> g, gc (in-register),
// then tg = Wd @ g via shfl broadcast, ret = <x1, tg> reductions.

__global__ __launch_bounds__(256) void k_readout(const float* __restrict__ mask,
                                                 const float* __restrict__ x1_all,
                                                 const float* __restrict__ Wd,
                                                 const float* __restrict__ bd,
                                                 float* __restrict__ ret1,
                                                 float* __restrict__ ret1c, int n) {
    int i = blockIdx.x;
    int lane = threadIdx.x & 63;
    int w = threadIdx.x >> 6;
    float acc = 0.f, accc = 0.f, rs = 0.f;
    const float* mrow = mask + (size_t)i * n;
    int quarter = n >> 2;           // 2048 columns per wave
    int qbase = w * quarter;
    int iters = quarter / 256;      // 8 (64 lanes x 4 elems)
    for (int it = 0; it < iters; ++it) {
        int jb = qbase + it * 256 + lane * 4;
        // nontemporal: the 256MB mask stream must not evict x1_all (4MB) from L2
        floatx4 q = __builtin_nontemporal_load(reinterpret_cast<const floatx4*>(mrow + jb));
        bool nz = (q[0] != 0.f) || (q[1] != 0.f) || (q[2] != 0.f) || (q[3] != 0.f);
        unsigned long long bal = __ballot(nz);
        while (bal) {
            int l = __builtin_ctzll(bal);
            bal &= bal - 1;
            float s0 = __shfl(q[0], l), s1 = __shfl(q[1], l);
            float s2 = __shfl(q[2], l), s3 = __shfl(q[3], l);
            int j0 = qbase + it * 256 + l * 4;
            float sv[4] = {s0, s1, s2, s3};
#pragma unroll
            for (int u = 0; u < 4; ++u) {
                if (sv[u] != 0.f) {
                    float m = sv[u];
                    int j = j0 + u;
                    acc += m * x1_all[(size_t)j * OUTD + lane];
                    accc += m * x1_all[(size_t)(n + j) * OUTD + lane];
                    rs += m;
                }
            }
        }
    }
    __shared__ float sa[4][64], sc[4][64], sr[4];
    sa[w][lane] = acc;
    sc[w][lane] = accc;
    if (lane == 0) sr[w] = rs;
    __syncthreads();
    if (w == 0) {
        float tot = sa[0][lane] + sa[1][lane] + sa[2][lane] + sa[3][lane];
        float totc = sc[0][lane] + sc[1][lane] + sc[2][lane] + sc[3][lane];
        float rst = fmaxf(sr[0] + sr[1] + sr[2] + sr[3], 1e-20f);
        float g = tot / rst;
        float gc = totc / rst;
        float s1 = g * g, s2 = gc * gc;
#pragma unroll
        for (int off = 32; off; off >>= 1) {
            s1 += __shfl_xor(s1, off);
            s2 += __shfl_xor(s2, off);
        }
        float gn = g / fmaxf(sqrtf(s1), 1e-12f);
        float gnc = gc / fmaxf(sqrtf(s2), 1e-12f);
        float gsig = 1.f / (1.f + __expf(-gn));
        float gcsig = 1.f / (1.f + __expf(-gnc));
        // ---- fused bilinear: tg[lane] = sum_j Wd[lane][j] * g[j] (shfl broadcast) ----
        float tg = 0.f, tgc = 0.f;
        const float* wrow = Wd + lane * 64;
#pragma unroll 8
        for (int j = 0; j < 64; ++j) {
            float gj = __shfl(gsig, j);
            float gcj = __shfl(gcsig, j);
            float wv = wrow[j];
            tg += wv * gj;
            tgc += wv * gcj;
        }
        float x = x1_all[(size_t)i * OUTD + lane];
        float xc = x1_all[(size_t)(n + i) * OUTD + lane];
        float r0 = x * tg, r1 = xc * tg, r2 = xc * tgc, r3 = x * tgc;
#pragma unroll
        for (int off = 32; off; off >>= 1) {
            r0 += __shfl_down(r0, off);
            r1 += __shfl_down(r1, off);
            r2 += __shfl_down(r2, off);
            r3 += __shfl_down(r3, off);
        }
        if (lane == 0) {
            float b = bd[0];
            ret1[(size_t)i * 2 + 0] = r0 + b;
            ret1[(size_t)i * 2 + 1] = r1 + b;
            ret1c[(size_t)i * 2 + 0] = r2 + b;
            ret1c[(size_t)i * 2 + 1] = r3 + b;
        }
    }
}

// ---------------- host ----------------

extern "C" void kernel_launch(void* const* d_in, const int* in_sizes, int n_in,
                              void* d_out, int out_size, void* d_ws, size_t ws_size,
                              hipStream_t stream) {
    const float* gene = (const float*)d_in[0];
    const float* mask = (const float*)d_in[1];
    const float* W1 = (const float*)d_in[2];
    const float* b1 = (const float*)d_in[3];
    const float* W2 = (const float*)d_in[4];
    const float* b2 = (const float*)d_in[5];
    const float* Wd = (const float*)d_in[6];
    const float* bd = (const float*)d_in[7];
    const unsigned* eidx_raw = (const unsigned*)d_in[8];
    const unsigned* perm_raw = (const unsigned*)d_in[9];
    const int n = NN;
    const int E = in_sizes[8] / 2;  // 131072 logical edge count

    // workspace carve-up (256B aligned); peak ~19.3 MB
    char* base = (char*)d_ws;
    char* p = base;
    auto alloc = [&](size_t bytes) -> char* {
        char* r = p;
        p += (bytes + 255) & ~(size_t)255;
        return r;
    };
    int* flags = (int*)alloc(256);
    int* eidx32 = (int*)alloc((size_t)2 * E * 4);
    int* perm32 = (int*)alloc((size_t)n * 4);
    int* deg = (int*)alloc((size_t)n * 4);
    int* row_ptr = (int*)alloc((size_t)(n + 1) * 4);
    int* cursor = (int*)alloc((size_t)n * 4);
    float* dinv = (float*)alloc((size_t)n * 4);
    int* col = (int*)alloc((size_t)E * 4);
    __hip_bfloat16* W2t = (__hip_bfloat16*)alloc((size_t)H1 * OUTD * 2);
    __hip_bfloat16* W1t = (__hip_bfloat16*)alloc((size_t)INDP * H1 * 2);  // padded ld
    float* xw1 = (float*)alloc((size_t)n * H1 * 4);                        // 8 MB
    __hip_bfloat16* h_all = (__hip_bfloat16*)alloc((size_t)2 * n * H1 * 2); // 8 MB
    size_t need = (size_t)(p - base);
    // aliases into dead buffers:
    float* hw_all = xw1;                         // 2n*64 fp32 = 4 MB (xw1 dead after agg1)
    float* x1_all = xw1 + (size_t)2 * n * OUTD;  // next 4 MB (exactly fills xw1's 8 MB)

    float* out_x1 = (float*)d_out;
    float* out_ret1 = out_x1 + (size_t)n * OUTD;
    float* out_ret1c = out_ret1 + (size_t)n * 2;

    if (ws_size < need) {
        k_probe<<<1, 64, 0, stream>>>(1000.f + (float)(ws_size >> 20), out_x1);
        return;
    }

    hipMemsetAsync(deg, 0, (size_t)n * 4, stream);

    // 0. index width detect (1 launch, 2 blocks) -> normalize + degree (1 launch)
    k_detect2<<<2, 256, 0, stream>>>(eidx_raw, perm_raw, 2048, flags);
    k_prep<<<(2 * E + n + 255) / 256, 256, 0, stream>>>(eidx_raw, perm_raw, flags,
                                                        eidx32, perm32, deg, E, n);
    const int* srcv = eidx32;
    const int* dstv = eidx32 + E;

    // 1. CSR
    k_scan<<<1, 1024, 0, stream>>>(deg, row_ptr, cursor, dinv, n);
    k_scatter<<<(E + 255) / 256, 256, 0, stream>>>(srcv, dstv, cursor, col, E);

    // 2. weight fp32->bf16 transposes (K-contiguous B operands); W1t rows padded to 3008
    k_transpose_f2b<<<(IND * H1 + 255) / 256, 256, 0, stream>>>(W1, W1t, IND, H1, INDP);
    k_transpose_f2b<<<(H1 * OUTD + 255) / 256, 256, 0, stream>>>(W2, W2t, H1, OUTD, H1);

    // 3. GEMM1: xw1 = gene @ W1 (BK=64, col-panels fastest for A reuse)
    k_gemm1<<<dim3(H1 / 64, n / 64), 256, 0, stream>>>(gene, W1t, xw1);

    // 4. conv1 aggregation (both graphs) -> h_all bf16 [2n x 256]
    k_agg1<<<n, H1, 0, stream>>>(xw1, row_ptr, col, dinv, perm32, b1, h_all, n);

    // 5. GEMM2: hw_all = h_all(bf16) @ W2  (writes into dead xw1 region)
    k_gemm2<<<dim3(2 * n / 64, OUTD / 64), 256, 0, stream>>>(h_all, W2t, hw_all, 2 * n, OUTD, H1);

    // 6. conv2 aggregation -> x1_all fp32 [2n x 64]; x1 also to d_out
    k_agg2<<<n / 4, 256, 0, stream>>>(hw_all, row_ptr, col, dinv, b2, x1_all, out_x1, n);

    // 7. readout + bilinear fused -> ret1, ret1_c
    k_readout<<<n, 256, 0, stream>>>(mask, x1_all, Wd, bd, out_ret1, out_ret1c, n);
}